// Round 10
// baseline (135.467 us; speedup 1.0000x reference)
//
#include <hip/hip_runtime.h>

#define BB 16
#define CIN 256
#define COUT 128
#define EE 512
#define HH 64
#define WW 64
#define HP 66   // padded spatial dim

typedef int v4i __attribute__((ext_vector_type(4)));
typedef int v16i __attribute__((ext_vector_type(16)));

// ===== MFMA-path ws layout (bytes) =====
//   bias1 [16][256] f32 @ 0        (16384)
//   bias2 [16][128] f32 @ 16384    (8192)
//   bias3 [16][128] f32 @ 24576    (8192)
//   A     [128] f32     @ 33280    (512)
//   B0    [128] f32     @ 33792    (512)
//   Wt    [9][128][256] i8 @ 34304 (294912)
//   S     [16][66][66][256] i8 @ 329216 (17842176)   total 18,171,392
// ===== fallback (R9) layout: ctab@34304, wq@38400, xpack@75264 =====

// ---------------------------------------------------------------- prep (MFMA)
__global__ __launch_bounds__(256) void prep2_k(
    const float* __restrict__ emb,
    const float* __restrict__ m1w, const float* __restrict__ m1b,
    const float* __restrict__ m2w, const float* __restrict__ m2b,
    const float* __restrict__ m3w, const float* __restrict__ m3b,
    const float* __restrict__ conv_w, const float* __restrict__ conv_b,
    const float* __restrict__ bn_g, const float* __restrict__ bn_b,
    const float* __restrict__ bn_m, const float* __restrict__ bn_v,
    float* __restrict__ bias1, float* __restrict__ bias2, float* __restrict__ bias3,
    float* __restrict__ A, float* __restrict__ B0,
    signed char* __restrict__ Wt)
{
    int bid = blockIdx.x;
    int tid = threadIdx.x;
    __shared__ float red[256];
    if (bid < 128) {
        int b = bid >> 3;
        int chunk = bid & 7;
        __shared__ float se[EE];
        {
            float v0 = emb[b * EE + tid];
            float v1 = emb[b * EE + tid + 256];
            se[tid] = v0 / (1.0f + __expf(-v0));
            se[tid + 256] = v1 / (1.0f + __expf(-v1));
        }
        __syncthreads();
        int cl = tid & 63;
        int ks = tid >> 6;
        const float* W;
        const float* Bv;
        float* dst;
        int c0;
        if (chunk < 4)      { c0 = chunk * 64;       W = m1w; Bv = m1b; dst = bias1 + b * CIN + c0; }
        else if (chunk < 6) { c0 = (chunk - 4) * 64; W = m2w; Bv = m2b; dst = bias2 + b * COUT + c0; }
        else                { c0 = (chunk - 6) * 64; W = m3w; Bv = m3b; dst = bias3 + b * COUT + c0; }
        const float4* w4 = (const float4*)(W + (size_t)(c0 + cl) * EE + ks * 128);
        const float* sp = &se[ks * 128];
        float acc = 0.f;
        #pragma unroll
        for (int e4 = 0; e4 < 32; ++e4) {
            float4 v = w4[e4];
            acc += sp[e4 * 4 + 0] * v.x + sp[e4 * 4 + 1] * v.y +
                   sp[e4 * 4 + 2] * v.z + sp[e4 * 4 + 3] * v.w;
        }
        red[tid] = acc;
        __syncthreads();
        if (ks == 0)
            dst[cl] = red[cl] + red[cl + 64] + red[cl + 128] + red[cl + 192] + Bv[c0 + cl];
    } else {
        int o = bid - 128;
        int c = tid;
        float wv[9];
        float asum = 0.f;
        const float* wp = conv_w + ((size_t)o * CIN + c) * 9;
        #pragma unroll
        for (int k = 0; k < 9; ++k) {
            float v = wp[k];
            wv[k] = v;
            asum += fabsf(v);
        }
        #pragma unroll
        for (int k = 0; k < 9; ++k)
            Wt[((size_t)k * COUT + o) * CIN + c] = (wv[k] > 0.f) ? (signed char)1 : (signed char)-1;
        red[tid] = asum;
        __syncthreads();
        for (int s = 128; s > 0; s >>= 1) {
            if (tid < s) red[tid] += red[tid + s];
            __syncthreads();
        }
        if (tid == 0) {
            float sc = red[0] * (1.0f / 2304.0f);
            float inv = bn_g[o] * rsqrtf(bn_v[o] + 1e-5f);
            A[o] = sc * inv;
            B0[o] = (conv_b[o] - bn_m[o]) * inv + bn_b[o];
        }
    }
}

// ---------------------------------------------------------------- sign (MFMA)
// 1024 blocks (b*64+h), 256 threads. Reads x coalesced (lane=w), LDS
// transpose, writes S[b][h+1][w+1][c] coalesced along c. Zero halo folded in.
__global__ __launch_bounds__(256) void sign_k(
    const float* __restrict__ x, const float* __restrict__ bias1,
    signed char* __restrict__ S)
{
    __shared__ unsigned int sl[64 * 65];   // [w][cgroup], +1 pitch
    __shared__ float sb[CIN];
    int bid = blockIdx.x;
    int b = bid >> 6;
    int h = bid & 63;
    int tid = threadIdx.x;

    // halo zeroing: 16 b * 260 ring cells * 256 B = 66560 16-B chunks
    if (bid < 260) {
        int hidx = bid * 256 + tid;
        if (hidx < 66560) {
            int cell = hidx >> 4;
            int inner = (hidx & 15) << 4;
            int b2 = cell / 260;
            int rem = cell % 260;
            int r, col;
            if (rem < 66)       { r = 0;  col = rem; }
            else if (rem < 132) { r = 65; col = rem - 66; }
            else                { int c2 = rem - 132; r = 1 + (c2 >> 1); col = (c2 & 1) * 65; }
            int4 z = make_int4(0, 0, 0, 0);
            *(int4*)(S + (((size_t)b2 * HP + r) * HP + col) * CIN + inner) = z;
        }
    }

    sb[tid] = bias1[b * CIN + tid];
    __syncthreads();

    int w = tid & 63;
    int q = tid >> 6;
    const float* xp = x + (size_t)b * CIN * (HH * WW) + (size_t)h * WW + w;
    #pragma unroll
    for (int cg = 0; cg < 16; ++cg) {
        int idx = q * 16 + cg;
        int c0 = idx * 4;
        unsigned int pk = 0;
        #pragma unroll
        for (int j = 0; j < 4; ++j) {
            float v = xp[(size_t)(c0 + j) * (HH * WW)] + sb[c0 + j];
            unsigned int byte = (v > 0.f) ? 0x01u : 0xFFu;
            pk |= byte << (8 * j);
        }
        sl[w * 65 + idx] = pk;
    }
    __syncthreads();

    int w2 = tid >> 2;
    int seg = tid & 3;
    signed char* dst = S + (((size_t)b * HP + h + 1) * HP + (w2 + 1)) * CIN + seg * 64;
    #pragma unroll
    for (int st = 0; st < 4; ++st) {
        int i0 = seg * 16 + st * 4;
        int4 v = make_int4((int)sl[w2 * 65 + i0 + 0], (int)sl[w2 * 65 + i0 + 1],
                           (int)sl[w2 * 65 + i0 + 2], (int)sl[w2 * 65 + i0 + 3]);
        *(int4*)(dst + st * 16) = v;
    }
}

// ---------------------------------------------------------------- main (MFMA)
// 1024 blocks (b*64+h), 256 threads = 4 waves (om = 32-o tile).
// Each wave: two 32x32 C-tiles (px 0-31, 32-63), K = 9 taps x 256 c.
// A frag: row=lane&31, k=(lane>>5)*16+j ; B frag: col=lane&31, same k.
// C/D: col=lane&31, row=(g&3)+8*(g>>2)+4*(lane>>5)  [verified m74/m101].
__global__ __launch_bounds__(256, 4) void main2_k(
    const signed char* __restrict__ Wt,    // [9][128][256]
    const signed char* __restrict__ S,     // [16][66][66][256]
    const float* __restrict__ x,
    const float* __restrict__ A, const float* __restrict__ B0,
    const float* __restrict__ bias2, const float* __restrict__ bias3,
    const float* __restrict__ prelu_a,
    float* __restrict__ out)
{
    int bid = blockIdx.x;
    int b = bid >> 6;
    int h = bid & 63;
    int tid = threadIdx.x;
    int l = tid & 63;
    int om = tid >> 6;       // wave-uniform o-tile
    int lr = l & 31;
    int lk = l >> 5;

    v16i acc0 = {};
    v16i acc1 = {};

    const signed char* abase = Wt + ((size_t)(om * 32 + lr)) * CIN + lk * 16;
    const signed char* bbase = S + (((size_t)b * HP + h) * HP) * CIN + lk * 16;

    #pragma unroll
    for (int t = 0; t < 9; ++t) {
        const int r = t / 3, dw = t % 3;
        const signed char* ap = abase + (size_t)t * COUT * CIN;
        const signed char* bp0 = bbase + ((size_t)r * HP + dw + lr) * CIN;
        const signed char* bp1 = bp0 + (size_t)32 * CIN;
        #pragma unroll
        for (int ck = 0; ck < 8; ++ck) {
            v4i a  = *(const v4i*)(ap  + ck * 32);
            v4i b0 = *(const v4i*)(bp0 + ck * 32);
            v4i b1 = *(const v4i*)(bp1 + ck * 32);
            acc0 = __builtin_amdgcn_mfma_i32_32x32x32_i8(a, b0, acc0, 0, 0, 0);
            acc1 = __builtin_amdgcn_mfma_i32_32x32x32_i8(a, b1, acc1, 0, 0, 0);
        }
    }

    #pragma unroll
    for (int g = 0; g < 16; ++g) {
        int o = om * 32 + (g & 3) + 8 * (g >> 2) + 4 * lk;
        float Ao = A[o], B0o = B0[o];
        float b2 = bias2[b * COUT + o], b3 = bias3[b * COUT + o], pa = prelu_a[o];
        const float* xr = x + ((size_t)(b * CIN + 2 * o)) * (HH * WW) + (size_t)h * WW;
        float* op = out + ((size_t)(b * COUT + o)) * (HH * WW) + (size_t)h * WW;
        {
            int w = lr;
            float cv = (float)acc0[g] * Ao + B0o;
            float r0 = xr[w], r1 = xr[HH * WW + w];
            float tv = cv + 0.5f * (r0 + r1) + b2;
            tv = tv > 0.f ? tv : pa * tv;
            op[w] = tv + b3;
        }
        {
            int w = 32 + lr;
            float cv = (float)acc1[g] * Ao + B0o;
            float r0 = xr[w], r1 = xr[HH * WW + w];
            float tv = cv + 0.5f * (r0 + r1) + b2;
            tv = tv > 0.f ? tv : pa * tv;
            op[w] = tv + b3;
        }
    }
}

// ================= fallback path (R9, proven @69.5us) =================
__global__ __launch_bounds__(256) void prep_f(
    const float* __restrict__ emb,
    const float* __restrict__ m1w, const float* __restrict__ m1b,
    const float* __restrict__ m2w, const float* __restrict__ m2b,
    const float* __restrict__ m3w, const float* __restrict__ m3b,
    const float* __restrict__ conv_w, const float* __restrict__ conv_b,
    const float* __restrict__ bn_g, const float* __restrict__ bn_b,
    const float* __restrict__ bn_m, const float* __restrict__ bn_v,
    float* __restrict__ bias1, float* __restrict__ bias2, float* __restrict__ bias3,
    float* __restrict__ A, float* __restrict__ B0,
    int* __restrict__ ctab, unsigned long long* __restrict__ wq)
{
    int bid = blockIdx.x;
    int tid = threadIdx.x;
    __shared__ float red[256];
    if (bid < 128) {
        int b = bid >> 3;
        int chunk = bid & 7;
        __shared__ float se[EE];
        {
            float v0 = emb[b * EE + tid];
            float v1 = emb[b * EE + tid + 256];
            se[tid] = v0 / (1.0f + __expf(-v0));
            se[tid + 256] = v1 / (1.0f + __expf(-v1));
        }
        __syncthreads();
        int cl = tid & 63;
        int ks = tid >> 6;
        const float* W;
        const float* Bv;
        float* dst;
        int c0;
        if (chunk < 4)      { c0 = chunk * 64;       W = m1w; Bv = m1b; dst = bias1 + b * CIN + c0; }
        else if (chunk < 6) { c0 = (chunk - 4) * 64; W = m2w; Bv = m2b; dst = bias2 + b * COUT + c0; }
        else                { c0 = (chunk - 6) * 64; W = m3w; Bv = m3b; dst = bias3 + b * COUT + c0; }
        const float4* w4 = (const float4*)(W + (size_t)(c0 + cl) * EE + ks * 128);
        const float* sp = &se[ks * 128];
        float acc = 0.f;
        #pragma unroll
        for (int e4 = 0; e4 < 32; ++e4) {
            float4 v = w4[e4];
            acc += sp[e4 * 4 + 0] * v.x + sp[e4 * 4 + 1] * v.y +
                   sp[e4 * 4 + 2] * v.z + sp[e4 * 4 + 3] * v.w;
        }
        red[tid] = acc;
        __syncthreads();
        if (ks == 0)
            dst[cl] = red[cl] + red[cl + 64] + red[cl + 128] + red[cl + 192] + Bv[c0 + cl];
    } else {
        int o = bid - 128;
        int i = tid;
        __shared__ int spc[36];
        float wv[9];
        float asum = 0.f;
        const float* wp = conv_w + ((size_t)o * CIN + i) * 9;
        #pragma unroll
        for (int k = 0; k < 9; ++k) {
            float v = wp[k];
            wv[k] = v;
            asum += fabsf(v);
        }
        int wave = tid >> 6;
        #pragma unroll
        for (int k = 0; k < 9; ++k) {
            unsigned long long m = __ballot(wv[k] > 0.0f);
            if ((tid & 63) == 0) {
                wq[((size_t)wave * COUT + o) * 9 + k] = m;
                spc[k * 4 + wave] = __popcll(m);
            }
        }
        red[tid] = asum;
        __syncthreads();
        for (int s = 128; s > 0; s >>= 1) {
            if (tid < s) red[tid] += red[tid + s];
            __syncthreads();
        }
        if (tid < 9)
            spc[tid] = spc[tid * 4 + 0] + spc[tid * 4 + 1] + spc[tid * 4 + 2] + spc[tid * 4 + 3];
        __syncthreads();
        if (tid == 0) {
            float sc = red[0] * (1.0f / 2304.0f);
            float inv = bn_g[o] * rsqrtf(bn_v[o] + 1e-5f);
            A[o] = sc * inv;
            B0[o] = (conv_b[o] - bn_m[o]) * inv + bn_b[o];
            int p0 = spc[0], p1 = spc[1], p2 = spc[2];
            int p3 = spc[3], p5 = spc[5];
            int p6 = spc[6], p7 = spc[7], p8 = spc[8];
            int* ct = ctab + o * 8;
            ct[0] = p0 + p1 + p2;
            ct[1] = p6 + p7 + p8;
            ct[2] = p0 + p3 + p6;
            ct[3] = p2 + p5 + p8;
            ct[4] = p0;
            ct[5] = p2;
            ct[6] = p6;
            ct[7] = p8;
        }
    }
}

__global__ __launch_bounds__(256) void pack_f(
    const float* __restrict__ x, const float* __restrict__ bias1,
    unsigned long long* __restrict__ xq)
{
    int bid = blockIdx.x;
    int b = bid >> 6;
    int h = bid & 63;
    int tid = threadIdx.x;
    int w = tid & 63;
    int q = tid >> 6;
    int idx = bid * 17 + tid;
    if (tid < 17 && idx < 16640) {
        int b2 = idx / 1040;
        int rem = idx % 1040;
        int cell = rem >> 2;
        int q2 = rem & 3;
        int r, col;
        if (cell < 66)       { r = 0;  col = cell; }
        else if (cell < 132) { r = 65; col = cell - 66; }
        else                 { int c2 = cell - 132; r = 1 + (c2 >> 1); col = (c2 & 1) * 65; }
        xq[(((size_t)b2 * HP + r) * HP + col) * 4 + q2] = 0ull;
    }
    __shared__ float sb[CIN];
    sb[tid] = bias1[b * CIN + tid];
    __syncthreads();
    const float* xp = x + ((size_t)b * CIN + (size_t)q * 64) * (HH * WW) + (size_t)h * WW + w;
    const float* bb = &sb[q * 64];
    unsigned long long m = 0;
    #pragma unroll
    for (int c = 0; c < 64; ++c) {
        if (xp[(size_t)c * (HH * WW)] + bb[c] > 0.f) m |= 1ull << c;
    }
    xq[(((size_t)b * HP + h + 1) * HP + (w + 1)) * 4 + q] = m;
}

__global__ __launch_bounds__(512, 4) void main_f(
    const unsigned long long* __restrict__ wq,
    const unsigned long long* __restrict__ xpack,
    const int* __restrict__ ctab,
    const float* __restrict__ x,
    const float* __restrict__ A, const float* __restrict__ B0,
    const float* __restrict__ bias2, const float* __restrict__ bias3,
    const float* __restrict__ prelu_a,
    float* __restrict__ out)
{
    __shared__ int Pacc[WW * (COUT + 1)];
    int bid = blockIdx.x;
    int b = bid >> 6;
    int h = bid & 63;
    int tid = threadIdx.x;
    int lane = tid & 63;
    int wid = __builtin_amdgcn_readfirstlane(tid >> 6);
    int q = wid & 3;
    int oh = wid >> 2;
    int o = oh * 64 + lane;
    #pragma unroll
    for (int i = 0; i < 17; ++i) {
        int idx = tid + i * 512;
        if (idx < WW * (COUT + 1)) Pacc[idx] = 0;
    }
    unsigned long long wl[9];
    {
        const unsigned long long* wp = wq + ((size_t)q * COUT + o) * 9;
        #pragma unroll
        for (int t = 0; t < 9; ++t) wl[t] = wp[t];
    }
    __syncthreads();
    const unsigned long long* xb = xpack + ((size_t)(b * HP + h) * HP) * 4 + q;
    #pragma unroll 4
    for (int w = 0; w < WW; ++w) {
        int P = 0;
        #pragma unroll
        for (int r = 0; r < 3; ++r) {
            #pragma unroll
            for (int dw = 0; dw < 3; ++dw) {
                unsigned long long xv = xb[(size_t)(r * HP + w + dw) * 4];
                P += __popcll(xv ^ wl[r * 3 + dw]);
            }
        }
        atomicAdd(&Pacc[w * (COUT + 1) + o], P);
    }
    __syncthreads();
    int hm = (h == 0) ? 1 : (h == 63) ? 2 : 0;
    #pragma unroll
    for (int i = 0; i < 16; ++i) {
        int idx = i * 512 + tid;
        int o2 = __builtin_amdgcn_readfirstlane(idx >> 6);
        int w2 = idx & 63;
        int P = Pacc[w2 * (COUT + 1) + o2];
        const int* ct = ctab + o2 * 8;
        int corr = 0, nvr = 3;
        int ctLa = ct[2], ctRa = ct[3];
        if (hm == 1) { corr += ct[0]; nvr = 2; ctLa -= ct[4]; ctRa -= ct[5]; }
        if (hm == 2) { corr += ct[1]; nvr = 2; ctLa -= ct[6]; ctRa -= ct[7]; }
        int m0  = (w2 == 0)  ? -1 : 0;
        int m63 = (w2 == 63) ? -1 : 0;
        int nvc = 3 + m0 + m63;
        corr += (m0 & ctLa) + (m63 & ctRa);
        float cv = (float)(nvr * nvc * 256 - 2 * (P - corr)) * A[o2] + B0[o2];
        float r0 = x[((size_t)(b * CIN + 2 * o2) * HH + h) * WW + w2];
        float r1 = x[((size_t)(b * CIN + 2 * o2 + 1) * HH + h) * WW + w2];
        float tv = cv + 0.5f * (r0 + r1) + bias2[b * COUT + o2];
        tv = tv > 0.f ? tv : prelu_a[o2] * tv;
        out[((size_t)(b * COUT + o2) * HH + h) * WW + w2] = tv + bias3[b * COUT + o2];
    }
}

extern "C" void kernel_launch(void* const* d_in, const int* in_sizes, int n_in,
                              void* d_out, int out_size, void* d_ws, size_t ws_size,
                              hipStream_t stream) {
    const float* x      = (const float*)d_in[0];
    const float* emb    = (const float*)d_in[1];
    const float* m1w    = (const float*)d_in[2];
    const float* m1b    = (const float*)d_in[3];
    const float* conv_w = (const float*)d_in[4];
    const float* conv_b = (const float*)d_in[5];
    const float* bn_g   = (const float*)d_in[6];
    const float* bn_b   = (const float*)d_in[7];
    const float* bn_m   = (const float*)d_in[8];
    const float* bn_v   = (const float*)d_in[9];
    const float* m2w    = (const float*)d_in[10];
    const float* m2b    = (const float*)d_in[11];
    const float* pa     = (const float*)d_in[12];
    const float* m3w    = (const float*)d_in[13];
    const float* m3b    = (const float*)d_in[14];
    float* out = (float*)d_out;

    char* ws = (char*)d_ws;
    float* bias1 = (float*)(ws + 0);
    float* bias2 = (float*)(ws + 16384);
    float* bias3 = (float*)(ws + 24576);
    float* Aarr  = (float*)(ws + 33280);
    float* B0arr = (float*)(ws + 33792);

    const size_t NEED = 329216 + (size_t)BB * HP * HP * CIN;   // 18,171,392
    if (ws_size >= NEED) {
        signed char* Wt = (signed char*)(ws + 34304);
        signed char* S  = (signed char*)(ws + 329216);
        prep2_k<<<256, 256, 0, stream>>>(emb, m1w, m1b, m2w, m2b, m3w, m3b,
                                         conv_w, conv_b, bn_g, bn_b, bn_m, bn_v,
                                         bias1, bias2, bias3, Aarr, B0arr, Wt);
        sign_k<<<BB * HH, 256, 0, stream>>>(x, bias1, S);
        main2_k<<<BB * HH, 256, 0, stream>>>(Wt, S, x, Aarr, B0arr,
                                             bias2, bias3, pa, out);
    } else {
        int*   ctab  = (int*)(ws + 34304);
        unsigned long long* wq    = (unsigned long long*)(ws + 38400);
        unsigned long long* xpack = (unsigned long long*)(ws + 75264);
        prep_f<<<256, 256, 0, stream>>>(emb, m1w, m1b, m2w, m2b, m3w, m3b,
                                        conv_w, conv_b, bn_g, bn_b, bn_m, bn_v,
                                        bias1, bias2, bias3, Aarr, B0arr, ctab, wq);
        pack_f<<<BB * HH, 256, 0, stream>>>(x, bias1, xpack);
        main_f<<<BB * HH, 512, 0, stream>>>(wq, xpack, ctab, x, Aarr, B0arr,
                                            bias2, bias3, pa, out);
    }
}

// Round 11
// 64.184 us; speedup vs baseline: 2.1106x; 2.1106x over previous
//
#include <hip/hip_runtime.h>

#define BB 16
#define CIN 256
#define COUT 128
#define EE 512
#define HH 64
#define WW 64
#define HP 66   // padded spatial dim
#define NCG 16  // CIN/16 chunks of 16 i8

typedef int v4i __attribute__((ext_vector_type(4)));
typedef int v16i __attribute__((ext_vector_type(16)));

// ws layout (bytes):
//   bias1 [16][256] f32 @ 0        (16384)
//   bias2 [16][128] f32 @ 16384    (8192)
//   bias3 [16][128] f32 @ 24576    (8192)
//   A     [128] f32     @ 33280    (512)
//   B0    [128] f32     @ 33792    (512)
//   Wt2   [9][16][128]x16B @ 34304 (294912)    (tap, c-chunk, o)
//   S2    [16][66][16][66]x16B @ 329216 (17842176)  (b, row, c-chunk, col)

__global__ __launch_bounds__(256) void prep2_k(
    const float* __restrict__ emb,
    const float* __restrict__ m1w, const float* __restrict__ m1b,
    const float* __restrict__ m2w, const float* __restrict__ m2b,
    const float* __restrict__ m3w, const float* __restrict__ m3b,
    const float* __restrict__ conv_w, const float* __restrict__ conv_b,
    const float* __restrict__ bn_g, const float* __restrict__ bn_b,
    const float* __restrict__ bn_m, const float* __restrict__ bn_v,
    float* __restrict__ bias1, float* __restrict__ bias2, float* __restrict__ bias3,
    float* __restrict__ A, float* __restrict__ B0,
    signed char* __restrict__ Wt)
{
    int bid = blockIdx.x;
    int tid = threadIdx.x;
    __shared__ float red[256];
    if (bid < 128) {
        int b = bid >> 3;
        int chunk = bid & 7;
        __shared__ float se[EE];
        {
            float v0 = emb[b * EE + tid];
            float v1 = emb[b * EE + tid + 256];
            se[tid] = v0 / (1.0f + __expf(-v0));
            se[tid + 256] = v1 / (1.0f + __expf(-v1));
        }
        __syncthreads();
        int cl = tid & 63;
        int ks = tid >> 6;
        const float* W;
        const float* Bv;
        float* dst;
        int c0;
        if (chunk < 4)      { c0 = chunk * 64;       W = m1w; Bv = m1b; dst = bias1 + b * CIN + c0; }
        else if (chunk < 6) { c0 = (chunk - 4) * 64; W = m2w; Bv = m2b; dst = bias2 + b * COUT + c0; }
        else                { c0 = (chunk - 6) * 64; W = m3w; Bv = m3b; dst = bias3 + b * COUT + c0; }
        const float4* w4 = (const float4*)(W + (size_t)(c0 + cl) * EE + ks * 128);
        const float* sp = &se[ks * 128];
        float acc = 0.f;
        #pragma unroll
        for (int e4 = 0; e4 < 32; ++e4) {
            float4 v = w4[e4];
            acc += sp[e4 * 4 + 0] * v.x + sp[e4 * 4 + 1] * v.y +
                   sp[e4 * 4 + 2] * v.z + sp[e4 * 4 + 3] * v.w;
        }
        red[tid] = acc;
        __syncthreads();
        if (ks == 0)
            dst[cl] = red[cl] + red[cl + 64] + red[cl + 128] + red[cl + 192] + Bv[c0 + cl];
    } else {
        int o = bid - 128;
        int c = tid;
        float wv[9];
        float asum = 0.f;
        const float* wp = conv_w + ((size_t)o * CIN + c) * 9;
        #pragma unroll
        for (int k = 0; k < 9; ++k) {
            float v = wp[k];
            wv[k] = v;
            asum += fabsf(v);
        }
        #pragma unroll
        for (int k = 0; k < 9; ++k)
            Wt[(((size_t)k * NCG + (c >> 4)) * COUT + o) * 16 + (c & 15)] =
                (wv[k] > 0.f) ? (signed char)1 : (signed char)-1;
        red[tid] = asum;
        __syncthreads();
        for (int s = 128; s > 0; s >>= 1) {
            if (tid < s) red[tid] += red[tid + s];
            __syncthreads();
        }
        if (tid == 0) {
            float sc = red[0] * (1.0f / 2304.0f);
            float inv = bn_g[o] * rsqrtf(bn_v[o] + 1e-5f);
            A[o] = sc * inv;
            B0[o] = (conv_b[o] - bn_m[o]) * inv + bn_b[o];
        }
    }
}

// 1024 blocks (b*64+h), 256 threads = 64 w x 4 q-groups; q handles 4 c-chunks.
// Writes S2[b][h+1][cg][w+1] — lanes (w) contiguous => coalesced 1KB stores.
// Zero halo folded in (blocks 0..259 also zero 256 ring-chunks each).
__global__ __launch_bounds__(256) void sign_k(
    const float* __restrict__ x, const float* __restrict__ bias1,
    signed char* __restrict__ S)
{
    __shared__ float sb[CIN];
    int bid = blockIdx.x;
    int b = bid >> 6;
    int h = bid & 63;
    int tid = threadIdx.x;

    // halo zeroing: 16 b * 260 ring cells * 16 cg = 66560 16-B chunks
    if (bid < 260) {
        int hidx = bid * 256 + tid;   // exactly 260*256 = 66560
        int cellg = hidx >> 4;
        int cg = hidx & 15;
        int b2 = cellg / 260;
        int rem = cellg % 260;
        int r, col;
        if (rem < 66)       { r = 0;  col = rem; }
        else if (rem < 132) { r = 65; col = rem - 66; }
        else                { int c2 = rem - 132; r = 1 + (c2 >> 1); col = (c2 & 1) * 65; }
        int4 z = make_int4(0, 0, 0, 0);
        *(int4*)(S + ((((size_t)b2 * HP + r) * NCG + cg) * HP + col) * 16) = z;
    }

    sb[tid] = bias1[b * CIN + tid];
    __syncthreads();

    int w = tid & 63;
    int q = tid >> 6;
    const float* xp = x + (size_t)b * CIN * (HH * WW) + (size_t)h * WW + w;
    #pragma unroll
    for (int st = 0; st < 4; ++st) {
        int cg = q * 4 + st;
        unsigned int pk0 = 0, pk1 = 0, pk2 = 0, pk3 = 0;
        #pragma unroll
        for (int j = 0; j < 4; ++j) {
            int c = cg * 16 + j;
            float t0 = xp[(size_t)(c +  0) * (HH * WW)] + sb[c +  0];
            float t1 = xp[(size_t)(c +  4) * (HH * WW)] + sb[c +  4];
            float t2 = xp[(size_t)(c +  8) * (HH * WW)] + sb[c +  8];
            float t3 = xp[(size_t)(c + 12) * (HH * WW)] + sb[c + 12];
            pk0 |= (t0 > 0.f ? 0x01u : 0xFFu) << (8 * j);
            pk1 |= (t1 > 0.f ? 0x01u : 0xFFu) << (8 * j);
            pk2 |= (t2 > 0.f ? 0x01u : 0xFFu) << (8 * j);
            pk3 |= (t3 > 0.f ? 0x01u : 0xFFu) << (8 * j);
        }
        int4 val = make_int4((int)pk0, (int)pk1, (int)pk2, (int)pk3);
        *(int4*)(S + ((((size_t)b * HP + (h + 1)) * NCG + cg) * HP + (w + 1)) * 16) = val;
    }
}

// 1024 blocks (b*64+h), 256 threads = 4 waves (om = 32-o tile).
// Each wave: two 32x32 C-tiles (px 0-31, 32-63), K = 9 taps x 256 c.
// Logical fragment mapping identical to R10 (verified); only the address
// functions changed: both A and B loads are now contiguous-512B per
// half-wave (k-major tiled layouts).
__global__ __launch_bounds__(256, 4) void main2_k(
    const signed char* __restrict__ Wt,    // [9][16][128]x16B
    const signed char* __restrict__ S,     // [16][66][16][66]x16B
    const float* __restrict__ x,
    const float* __restrict__ A, const float* __restrict__ B0,
    const float* __restrict__ bias2, const float* __restrict__ bias3,
    const float* __restrict__ prelu_a,
    float* __restrict__ out)
{
    int bid = blockIdx.x;
    int b = bid >> 6;
    int h = bid & 63;
    int tid = threadIdx.x;
    int l = tid & 63;
    int om = tid >> 6;       // wave-uniform o-tile
    int lr = l & 31;
    int lk = l >> 5;

    v16i acc0 = {};
    v16i acc1 = {};

    const signed char* abase = Wt + ((size_t)lk * COUT + om * 32 + lr) * 16;
    const signed char* bbase = S + ((((size_t)b * HP + h) * NCG + lk) * HP + lr) * 16;

    #pragma unroll
    for (int t = 0; t < 9; ++t) {
        const int r = t / 3, dw = t % 3;
        const signed char* ap = abase + (size_t)t * NCG * COUT * 16;
        const signed char* bp = bbase + ((size_t)r * NCG * HP + dw) * 16;
        #pragma unroll
        for (int ck = 0; ck < 8; ++ck) {
            v4i a  = *(const v4i*)(ap + (size_t)ck * 2 * COUT * 16);
            v4i b0 = *(const v4i*)(bp + (size_t)ck * 2 * HP * 16);
            v4i b1 = *(const v4i*)(bp + (size_t)ck * 2 * HP * 16 + 32 * 16);
            acc0 = __builtin_amdgcn_mfma_i32_32x32x32_i8(a, b0, acc0, 0, 0, 0);
            acc1 = __builtin_amdgcn_mfma_i32_32x32x32_i8(a, b1, acc1, 0, 0, 0);
        }
    }

    #pragma unroll
    for (int g = 0; g < 16; ++g) {
        int o = om * 32 + (g & 3) + 8 * (g >> 2) + 4 * lk;
        float Ao = A[o], B0o = B0[o];
        float b2 = bias2[b * COUT + o], b3 = bias3[b * COUT + o], pa = prelu_a[o];
        const float* xr = x + ((size_t)(b * CIN + 2 * o)) * (HH * WW) + (size_t)h * WW;
        float* op = out + ((size_t)(b * COUT + o)) * (HH * WW) + (size_t)h * WW;
        {
            int w = lr;
            float cv = (float)acc0[g] * Ao + B0o;
            float r0 = xr[w], r1 = xr[HH * WW + w];
            float tv = cv + 0.5f * (r0 + r1) + b2;
            tv = tv > 0.f ? tv : pa * tv;
            op[w] = tv + b3;
        }
        {
            int w = 32 + lr;
            float cv = (float)acc1[g] * Ao + B0o;
            float r0 = xr[w], r1 = xr[HH * WW + w];
            float tv = cv + 0.5f * (r0 + r1) + b2;
            tv = tv > 0.f ? tv : pa * tv;
            op[w] = tv + b3;
        }
    }
}

extern "C" void kernel_launch(void* const* d_in, const int* in_sizes, int n_in,
                              void* d_out, int out_size, void* d_ws, size_t ws_size,
                              hipStream_t stream) {
    const float* x      = (const float*)d_in[0];
    const float* emb    = (const float*)d_in[1];
    const float* m1w    = (const float*)d_in[2];
    const float* m1b    = (const float*)d_in[3];
    const float* conv_w = (const float*)d_in[4];
    const float* conv_b = (const float*)d_in[5];
    const float* bn_g   = (const float*)d_in[6];
    const float* bn_b   = (const float*)d_in[7];
    const float* bn_m   = (const float*)d_in[8];
    const float* bn_v   = (const float*)d_in[9];
    const float* m2w    = (const float*)d_in[10];
    const float* m2b    = (const float*)d_in[11];
    const float* pa     = (const float*)d_in[12];
    const float* m3w    = (const float*)d_in[13];
    const float* m3b    = (const float*)d_in[14];
    float* out = (float*)d_out;

    char* ws = (char*)d_ws;
    float* bias1 = (float*)(ws + 0);
    float* bias2 = (float*)(ws + 16384);
    float* bias3 = (float*)(ws + 24576);
    float* Aarr  = (float*)(ws + 33280);
    float* B0arr = (float*)(ws + 33792);
    signed char* Wt = (signed char*)(ws + 34304);
    signed char* S  = (signed char*)(ws + 329216);

    prep2_k<<<256, 256, 0, stream>>>(emb, m1w, m1b, m2w, m2b, m3w, m3b,
                                     conv_w, conv_b, bn_g, bn_b, bn_m, bn_v,
                                     bias1, bias2, bias3, Aarr, B0arr, Wt);
    sign_k<<<BB * HH, 256, 0, stream>>>(x, bias1, S);
    main2_k<<<BB * HH, 256, 0, stream>>>(Wt, S, x, Aarr, B0arr,
                                         bias2, bias3, pa, out);
}